// Round 17
// baseline (162.668 us; speedup 1.0000x reference)
//
#include <hip/hip_runtime.h>

#define NTOT 100000

typedef float f32x4 __attribute__((ext_vector_type(4)));
typedef float f32x2 __attribute__((ext_vector_type(2)));
typedef short s16x8 __attribute__((ext_vector_type(8)));
typedef short s16x4 __attribute__((ext_vector_type(4)));
typedef unsigned int u32x2 __attribute__((ext_vector_type(2)));
typedef unsigned short u16;
typedef unsigned int u32;

__device__ __forceinline__ u16 bfbits(float f) {
    return __builtin_bit_cast(u16, (__bf16)f);
}
__device__ __forceinline__ u32 packbf2(float a, float b) {
    return (u32)bfbits(a) | ((u32)bfbits(b) << 16);
}
__device__ __forceinline__ float bf2f(u16 u) {
    u32 v = ((u32)u) << 16;
    return __builtin_bit_cast(float, v);
}
__device__ __forceinline__ s16x8 cvt8(const float* __restrict__ p) {
    f32x4 lo = *(const f32x4*)p;
    f32x4 hi = *(const f32x4*)(p + 4);
    s16x8 r;
#pragma unroll
    for (int e = 0; e < 4; ++e) r[e] = (short)bfbits(lo[e]);
#pragma unroll
    for (int e = 0; e < 4; ++e) r[4 + e] = (short)bfbits(hi[e]);
    return r;
}

// ds_read_b64_tr_b16 (HW-verified r7): per-lane addr = subtile_base + l15*8
// yields lane k, elem j = subtile[row j][col k] of a [4][16]-bf16 tile.
__device__ __forceinline__ s16x4 trread(unsigned a) {
    s16x4 d;
    asm volatile("ds_read_b64_tr_b16 %0, %1" : "=v"(d) : "v"(a));
    return d;
}
__device__ __forceinline__ s16x4 trread1k(unsigned a) {
    s16x4 d;
    asm volatile("ds_read_b64_tr_b16 %0, %1 offset:1024" : "=v"(d) : "v"(a));
    return d;
}
__device__ __forceinline__ s16x4 trread2k(unsigned a) {
    s16x4 d;
    asm volatile("ds_read_b64_tr_b16 %0, %1 offset:2048" : "=v"(d) : "v"(a));
    return d;
}
struct S2 { s16x4 lo, hi; };
__device__ __forceinline__ s16x8 cat44(s16x4 lo, s16x4 hi) {
    S2 s{lo, hi};
    return __builtin_bit_cast(s16x8, s);
}
// rule 18: lgkmcnt(0) + sched_barrier after inline-asm ds reads
#define LGKM0_FENCE()                                         \
    do {                                                      \
        asm volatile("s_waitcnt lgkmcnt(0)" ::: "memory");    \
        __builtin_amdgcn_sched_barrier(0);                    \
    } while (0)

// ---------------- kernel 2: P_partial(bf16) = E^T @ x --------------------
// r14-verified k-half kernel (512 blocks = 256 chunks x 2 k-halves, 512 thr,
// 2 blocks/CU -> 2.3 TB/s duty) + r17 change: XCD-PAIRING REMAP. Dispatch d
// -> chunk=(d>>4)*8+(d&7), kh=(d>>3)&1: both halves of a chunk are == mod 8
// (same XCD under round-robin heuristic) and 8 dispatches apart (temporally
// adjacent) -> 2nd half's X-window reads hit that XCD's L2, and both halves'
// partial writes stay in one L2 (r14's +73MB FETCH / 2x WRITE eliminated).
__global__ __launch_bounds__(512, 4) void k_gemm1(
    const float* __restrict__ E, const float* __restrict__ X,
    u16* __restrict__ Pp, int NB) {
    __shared__ alignas(16) u16 Et[2][4096];   // 2 x 8 KB
    __shared__ alignas(16) u16 Xt[2][8192];   // 2 x 16 KB

    int d = blockIdx.x;
    int chunk = (d >> 4) * 8 + (d & 7);    // 0..255
    int kh = (d >> 3) & 1, k0 = kh * 128;
    int nStart = chunk * NB;
    int nEnd = min(nStart + NB, NTOT);
    if (nEnd <= nStart) return;

    int t = threadIdx.x, lane = t & 63, w = t >> 6;   // w = 0..7
    int wk = w & 1, wi = w >> 1;           // compute: 64k x 64i per wave
    int l15 = lane & 15, lhi = lane >> 4;
    int lq = lane >> 2, ld = lane & 3;     // staging: col-quad, row-rot

    unsigned EtB = (unsigned)(size_t)&Et[0][0];
    unsigned XtB = (unsigned)(size_t)&Xt[0][0];

    // tr-read bases: Et subtile (ng,cg) at (ng*8+cg)*128, ng=2*lhi, cg=wk*4+m
    unsigned aB = EtB + (unsigned)(lhi * 2048 + wk * 512 + l15 * 8);
    // Xt subtile (ng,cg) at (ng*16+cg)*128, cg = wi*4+c
    unsigned bB = XtB + (unsigned)(lhi * 4096 + wi * 512 + l15 * 8);

    f32x4 vE[2], vX[4];
    f32x4 acc[4][4] = {};
    int nwin = (nEnd - nStart + 31) >> 5;

#define G1_LOAD(WIN)                                                        \
    {                                                                       \
        int n0_ = nStart + (WIN) * 32 + w * 4;                              \
        _Pragma("unroll") for (int qe = 0; qe < 2; ++qe) {                  \
            int r_ = n0_ + ((ld + qe) & 3);                                 \
            int a_ = (r_ < nEnd) ? r_ : nStart;                             \
            float m_ = (r_ < nEnd) ? 1.f : 0.f;                             \
            vE[qe] = *(const f32x4*)(E + (size_t)a_ * 256 + k0 +            \
                                     (qe * 16 + lq) * 4) * m_;              \
        }                                                                   \
        _Pragma("unroll") for (int q = 0; q < 4; ++q) {                     \
            int r_ = n0_ + ((ld + q) & 3);                                  \
            int a_ = (r_ < nEnd) ? r_ : nStart;                             \
            float m_ = (r_ < nEnd) ? 1.f : 0.f;                             \
            vX[q] = *(const f32x4*)(X + (size_t)a_ * 256 +                  \
                                    (q * 16 + lq) * 4) * m_;                \
        }                                                                   \
    }

#define G1_WRITE(BUF)                                                       \
    {                                                                       \
        _Pragma("unroll") for (int qe = 0; qe < 2; ++qe) {                  \
            int g_ = qe * 16 + lq, d_ = (ld + qe) & 3;                      \
            unsigned by_ = (unsigned)(BUF) * 8192u +                        \
                (unsigned)((w * 8 + (g_ >> 2)) * 128 + d_ * 32 + (g_ & 3) * 8); \
            *(u32x2*)((char*)Et + by_) =                                    \
                (u32x2){packbf2(vE[qe][0], vE[qe][1]),                      \
                        packbf2(vE[qe][2], vE[qe][3])};                     \
        }                                                                   \
        _Pragma("unroll") for (int q = 0; q < 4; ++q) {                     \
            int g_ = q * 16 + lq, d_ = (ld + q) & 3;                        \
            unsigned by_ = (unsigned)(BUF) * 16384u +                       \
                (unsigned)((w * 16 + (g_ >> 2)) * 128 + d_ * 32 + (g_ & 3) * 8); \
            *(u32x2*)((char*)Xt + by_) =                                    \
                (u32x2){packbf2(vX[q][0], vX[q][1]),                        \
                        packbf2(vX[q][2], vX[q][3])};                       \
        }                                                                   \
    }

#define G1_COMPUTE(BUF)                                                     \
    {                                                                       \
        unsigned aB_ = aB + (unsigned)(BUF) * 8192u;                        \
        unsigned bB_ = bB + (unsigned)(BUF) * 16384u;                       \
        s16x4 ta0[4], ta1[4], tb0[4], tb1[4];                               \
        _Pragma("unroll") for (int m = 0; m < 4; ++m) {                     \
            ta0[m] = trread(aB_ + m * 128);                                 \
            ta1[m] = trread1k(aB_ + m * 128);                               \
        }                                                                   \
        _Pragma("unroll") for (int c = 0; c < 4; ++c) {                     \
            tb0[c] = trread(bB_ + c * 128);                                 \
            tb1[c] = trread2k(bB_ + c * 128);                               \
        }                                                                   \
        LGKM0_FENCE();                                                      \
        s16x8 a[4], b[4];                                                   \
        _Pragma("unroll") for (int m = 0; m < 4; ++m) a[m] = cat44(ta0[m], ta1[m]); \
        _Pragma("unroll") for (int c = 0; c < 4; ++c) b[c] = cat44(tb0[c], tb1[c]); \
        _Pragma("unroll") for (int m = 0; m < 4; ++m)                       \
            _Pragma("unroll") for (int c = 0; c < 4; ++c)                   \
                acc[m][c] = __builtin_amdgcn_mfma_f32_16x16x32_bf16(        \
                    a[m], b[c], acc[m][c], 0, 0, 0);                        \
    }

    G1_LOAD(0);
    G1_WRITE(0);
    G1_LOAD(1);
    asm volatile("s_waitcnt lgkmcnt(0)" ::: "memory");
    __builtin_amdgcn_s_barrier();
    for (int win = 0; win < nwin; ++win) {
        int cur = win & 1;
        G1_COMPUTE(cur);
        if (win + 1 < nwin) G1_WRITE(cur ^ 1);
        if (win + 2 < nwin) G1_LOAD(win + 2);
        asm volatile("s_waitcnt lgkmcnt(0)" ::: "memory");
        __builtin_amdgcn_s_barrier();
    }
#undef G1_LOAD
#undef G1_WRITE
#undef G1_COMPUTE

    u16* dst = Pp + (size_t)chunk * 65536;
#pragma unroll
    for (int m = 0; m < 4; ++m) {
#pragma unroll
        for (int cf = 0; cf < 4; ++cf) {
            int ii = wi * 64 + cf * 16 + l15;
#pragma unroll
            for (int r = 0; r < 4; ++r) {
                int kk = k0 + wk * 64 + m * 16 + lhi * 4 + r;
                dst[kk * 256 + ii] = bfbits(acc[m][cf][r]);
            }
        }
    }
}

// ---------------- kernel 3a: partial reduce (16 groups x 16 chunks) ------
__global__ void k_reduceA(const u32* __restrict__ Pp32,
                          f32x2* __restrict__ Pf, int cpg) {
    int g = blockIdx.x >> 7;                 // group
    int idx = (blockIdx.x & 127) * 256 + threadIdx.x;   // 0..32767
    int c0 = g * cpg;
    float s0 = 0.f, s1 = 0.f;
    for (int c = c0; c < c0 + cpg; ++c) {
        u32 vv = Pp32[(size_t)c * 32768 + idx];
        s0 += bf2f((u16)(vv & 0xffff));
        s1 += bf2f((u16)(vv >> 16));
    }
    Pf[(size_t)g * 32768 + idx] = (f32x2){s0, s1};
}

// ---------------- kernel 3b: final reduce -> Pb (bf16) -------------------
__global__ void k_reduceB(const f32x2* __restrict__ Pf,
                          u32* __restrict__ Pb32, int G) {
    int idx = blockIdx.x * 256 + threadIdx.x;   // 0..32767
    float s0 = 0.f, s1 = 0.f;
    for (int g = 0; g < G; ++g) {
        f32x2 v = Pf[(size_t)g * 32768 + idx];
        s0 += v[0]; s1 += v[1];
    }
    Pb32[idx] = packbf2(s0, s1);
}

// ---------------- kernel 4: T[c] = P @ W_c^T (17 small GEMMs) ------------
__global__ __launch_bounds__(256, 4) void k_smallgemm(
    const u16* __restrict__ Pb, const float* __restrict__ c0,
    const float* __restrict__ cjr, const float* __restrict__ cji,
    float* __restrict__ T) {
    int c = blockIdx.x >> 3;
    int k0 = (blockIdx.x & 7) * 32;
    const float* W = (c == 0) ? c0 : (c <= 8 ? (cjr + (size_t)(c - 1) * 65536)
                                             : (cji + (size_t)(c - 9) * 65536));
    int t = threadIdx.x, lane = t & 63, wi = t >> 6;
    int l15 = lane & 15, lhi = lane >> 4;
    f32x4 acc[2][4] = {};
    for (int is = 0; is < 256; is += 32) {
        s16x8 a[2], b[4];
#pragma unroll
        for (int m = 0; m < 2; ++m)
            a[m] = *(const s16x8*)(Pb + (k0 + m * 16 + l15) * 256 + is + lhi * 8);
#pragma unroll
        for (int cf = 0; cf < 4; ++cf)
            b[cf] = cvt8(W + (size_t)(wi * 64 + cf * 16 + l15) * 256 + is + lhi * 8);
#pragma unroll
        for (int m = 0; m < 2; ++m)
#pragma unroll
            for (int cf = 0; cf < 4; ++cf)
                acc[m][cf] = __builtin_amdgcn_mfma_f32_16x16x32_bf16(
                    a[m], b[cf], acc[m][cf], 0, 0, 0);
    }
    float* dst = T + (size_t)c * 65536;
#pragma unroll
    for (int m = 0; m < 2; ++m) {
#pragma unroll
        for (int cf = 0; cf < 4; ++cf) {
            int oo = wi * 64 + cf * 16 + l15;
#pragma unroll
            for (int r = 0; r < 4; ++r) {
                int kk = k0 + m * 16 + lhi * 4 + r;
                dst[kk * 256 + oo] = acc[m][cf][r];
            }
        }
    }
}

// ---------------- kernel 5: combine T -> Qt bf16 (weights fused) ---------
__global__ void k_combine(const float* __restrict__ T, const float* __restrict__ ev,
                          const float* __restrict__ hp, const float* __restrict__ ap,
                          u16* __restrict__ Qt) {
    int t = threadIdx.x;
    int k = blockIdx.x * 4 + (t >> 6);
    int o4 = (t & 63) * 4;
    float h = hp[0], alpha = ap[0];
    float tt = h * (ev[k] - alpha);
    float inv = 1.0f / (tt * tt + 1.0f);
    float bre = (tt * tt - 1.0f) * inv;
    float bim = -2.0f * tt * inv;
    float cr = bre, ci = bim;
    f32x4 q = *(const f32x4*)(T + (size_t)k * 256 + o4);
#pragma unroll
    for (int j = 0; j < 8; ++j) {
        f32x4 tr = *(const f32x4*)(T + (size_t)(1 + j) * 65536 + k * 256 + o4);
        f32x4 ti = *(const f32x4*)(T + (size_t)(9 + j) * 65536 + k * 256 + o4);
        q += 2.0f * (cr * tr - ci * ti);
        float nr = cr * bre - ci * bim;
        float ni = cr * bim + ci * bre;
        cr = nr; ci = ni;
    }
#pragma unroll
    for (int e = 0; e < 4; ++e) Qt[(size_t)(o4 + e) * 256 + k] = bfbits(q[e]);
}

// ---------------- kernel 6: out = E @ Q ----------------------------------
// r8-proven (reg-staged depth-2 pipeline, XCD swizzle); ~26 us, near floor.
__global__ __launch_bounds__(512, 4) void k_gemm2(
    const float* __restrict__ E, const u16* __restrict__ Qt,
    float* __restrict__ out) {
    __shared__ alignas(16) u16 Ebuf[2][32 * 256];   // 2 x 16 KB

    int b0 = blockIdx.x;
    int b = (b0 & 7) * 64 + (b0 >> 3);   // bijective XCD swizzle (512 = 8*64)
    int og = b & 1;
    int slab = b >> 1;                   // 0..255
    int tile0 = slab * 12 + min(slab, 53);   // 3125 = 256*12 + 53
    int nt = (slab < 53) ? 13 : 12;

    int t = threadIdx.x, lane = t & 63, w = t >> 6;
    int l15 = lane & 15, lhi = lane >> 4;
    int wn = w & 1, wo = w >> 1;         // wo 0..3
    int obase = og * 128 + wo * 32;
    int nrow = wn * 16 + l15;

    s16x8 af[2][8];
#pragma unroll
    for (int m = 0; m < 2; ++m)
#pragma unroll
        for (int ks = 0; ks < 8; ++ks)
            af[m][ks] = *(const s16x8*)(Qt + (size_t)(obase + m * 16 + l15) * 256 +
                                        ks * 32 + lhi * 8);

    f32x4 rvA[4], rvB[4];

#define G2_LOADE(TI, RV)                                                    \
    {                                                                       \
        int nb0_ = (tile0 + (TI)) * 32 + w * 4;                             \
        _Pragma("unroll") for (int j = 0; j < 4; ++j)                       \
            RV[j] = *(const f32x4*)(E + (size_t)(nb0_ + j) * 256 + lane * 4); \
    }

#define G2_WRITEE(RV, BUF)                                                  \
    _Pragma("unroll") for (int j = 0; j < 4; ++j) {                         \
        int r_ = w * 4 + j;                                                 \
        *(u32x2*)((char*)Ebuf[BUF] + r_ * 512 +                             \
                  (((lane >> 1) ^ (r_ & 7)) * 16) + (lane & 1) * 8) =       \
            (u32x2){packbf2(RV[j][0], RV[j][1]), packbf2(RV[j][2], RV[j][3])}; \
    }

#define G2_TILE(I, BUF, WRV, LRV)                                           \
    {                                                                       \
        f32x4 acc[2] = {};                                                  \
        const char* Eb_ = (const char*)Ebuf[BUF];                           \
        _Pragma("unroll") for (int ks = 0; ks < 8; ++ks) {                  \
            s16x8 ef = *(const s16x8*)(Eb_ + nrow * 512 +                   \
                        (((ks * 4 + lhi) ^ (nrow & 7)) * 16));              \
            _Pragma("unroll") for (int m = 0; m < 2; ++m)                   \
                acc[m] = __builtin_amdgcn_mfma_f32_16x16x32_bf16(           \
                    af[m][ks], ef, acc[m], 0, 0, 0);                        \
        }                                                                   \
        int n_ = (tile0 + (I)) * 32 + wn * 16 + l15;                        \
        _Pragma("unroll") for (int m = 0; m < 2; ++m)                       \
            *(f32x4*)(out + (size_t)n_ * 256 + obase + m * 16 + lhi * 4) =  \
                acc[m];                                                     \
        if ((I) + 1 < nt) G2_WRITEE(WRV, (BUF) ^ 1);                        \
        if ((I) + 2 < nt) G2_LOADE((I) + 2, LRV);                           \
        asm volatile("s_waitcnt lgkmcnt(0)" ::: "memory");                  \
        __builtin_amdgcn_s_barrier();                                       \
    }

    G2_LOADE(0, rvA);
    G2_WRITEE(rvA, 0);                    // prologue vmcnt stall (once)
    G2_LOADE(1, rvB);
    asm volatile("s_waitcnt lgkmcnt(0)" ::: "memory");
    __builtin_amdgcn_s_barrier();

    for (int i = 0; i < nt; i += 2) {
        G2_TILE(i, 0, rvB, rvA);          // even tile: buf0; write rvB->buf1
        if (i + 1 < nt)
            G2_TILE(i + 1, 1, rvA, rvB);  // odd tile: buf1; write rvA->buf0
    }
#undef G2_LOADE
#undef G2_WRITEE
#undef G2_TILE
}

// ---------------- host ---------------------------------------------------
extern "C" void kernel_launch(void* const* d_in, const int* in_sizes, int n_in,
                              void* d_out, int out_size, void* d_ws, size_t ws_size,
                              hipStream_t stream) {
    const float* x   = (const float*)d_in[0];
    const float* ev  = (const float*)d_in[1];
    const float* E   = (const float*)d_in[2];
    const float* hp  = (const float*)d_in[3];
    const float* ap  = (const float*)d_in[4];
    const float* c0  = (const float*)d_in[5];
    const float* cjr = (const float*)d_in[6];
    const float* cji = (const float*)d_in[7];
    float* out = (float*)d_out;

    char* ws = (char*)d_ws;
    u16*   Pb = (u16*)(ws + 16384);               // 128 KB
    u16*   Qt = (u16*)(ws + 147456);              // 128 KB
    float* T  = (float*)(ws + 278528);            // 17*256 KB -> 4.73 MB

    // d_out scratch layout (102.4 MB total), consumed before gemm2
    // overwrites it (stream-ordered), all regions fully written every call:
    //   [0, 33.55 MB)       Pp: 256 chunks x 128 KB bf16 partials
    //   [33.55, 37.75 MB)   Pf: 16 groups x 32768 f32x2 partial sums
    u16* Pp = (u16*)d_out;
    f32x2* Pf = (f32x2*)((char*)d_out + 33554432);
    const int chunks = 256;
    const int NB = 391;                           // 256*391 = 100096 >= NTOT
    const int G = 16, CPG = 16;                   // 16*16 = 256 exact

    k_gemm1<<<2 * chunks, 512, 0, stream>>>(E, x, Pp, NB);
    k_reduceA<<<G * 128, 256, 0, stream>>>((const u32*)Pp, Pf, CPG);
    k_reduceB<<<128, 256, 0, stream>>>(Pf, (u32*)Pb, G);
    k_smallgemm<<<17 * 8, 256, 0, stream>>>(Pb, c0, cjr, cji, T);
    k_combine<<<64, 256, 0, stream>>>(T, ev, hp, ap, Qt);
    k_gemm2<<<512, 512, 0, stream>>>(E, Qt, out);
}

// Round 18
// 130.301 us; speedup vs baseline: 1.2484x; 1.2484x over previous
//
#include <hip/hip_runtime.h>

#define NTOT 100000

typedef float f32x4 __attribute__((ext_vector_type(4)));
typedef float f32x2 __attribute__((ext_vector_type(2)));
typedef short s16x8 __attribute__((ext_vector_type(8)));
typedef short s16x4 __attribute__((ext_vector_type(4)));
typedef unsigned int u32x2 __attribute__((ext_vector_type(2)));
typedef unsigned short u16;
typedef unsigned int u32;

__device__ __forceinline__ u16 bfbits(float f) {
    return __builtin_bit_cast(u16, (__bf16)f);
}
__device__ __forceinline__ u32 packbf2(float a, float b) {
    return (u32)bfbits(a) | ((u32)bfbits(b) << 16);
}
__device__ __forceinline__ float bf2f(u16 u) {
    u32 v = ((u32)u) << 16;
    return __builtin_bit_cast(float, v);
}
__device__ __forceinline__ s16x8 cvt8(const float* __restrict__ p) {
    f32x4 lo = *(const f32x4*)p;
    f32x4 hi = *(const f32x4*)(p + 4);
    s16x8 r;
#pragma unroll
    for (int e = 0; e < 4; ++e) r[e] = (short)bfbits(lo[e]);
#pragma unroll
    for (int e = 0; e < 4; ++e) r[4 + e] = (short)bfbits(hi[e]);
    return r;
}

// ds_read_b64_tr_b16 (HW-verified r7): per-lane addr = subtile_base + l15*8
// yields lane k, elem j = subtile[row j][col k] of a [4][16]-bf16 tile.
__device__ __forceinline__ s16x4 trread(unsigned a) {
    s16x4 d;
    asm volatile("ds_read_b64_tr_b16 %0, %1" : "=v"(d) : "v"(a));
    return d;
}
__device__ __forceinline__ s16x4 trread2k(unsigned a) {
    s16x4 d;
    asm volatile("ds_read_b64_tr_b16 %0, %1 offset:2048" : "=v"(d) : "v"(a));
    return d;
}
struct S2 { s16x4 lo, hi; };
__device__ __forceinline__ s16x8 cat44(s16x4 lo, s16x4 hi) {
    S2 s{lo, hi};
    return __builtin_bit_cast(s16x8, s);
}
// rule 18: lgkmcnt(0) + sched_barrier after inline-asm ds reads
#define LGKM0_FENCE()                                         \
    do {                                                      \
        asm volatile("s_waitcnt lgkmcnt(0)" ::: "memory");    \
        __builtin_amdgcn_sched_barrier(0);                    \
    } while (0)

// ---------------- kernel 2: P_partial(bf16) = E^T @ x --------------------
// r15-exact, the measured optimum (88-92 us) of the explored trade-space:
// 256 chunks x 1024 thr (16 waves), full 256k x 256i per block; 32n
// windows, dbuf LDS, tr-read fragments. The 256KB accumulator forces
// 1 block/CU; all output-splits (r12/r14/r17) added input or write
// traffic and measured 102-107 us.
__global__ __launch_bounds__(1024, 4) void k_gemm1(
    const float* __restrict__ E, const float* __restrict__ X,
    u16* __restrict__ Pp, int NB) {
    __shared__ alignas(16) u16 Et[2][8192];   // 2 x 16 KB subtiled
    __shared__ alignas(16) u16 Xt[2][8192];   // 2 x 16 KB

    int chunk = blockIdx.x;
    int nStart = chunk * NB;
    int nEnd = min(nStart + NB, NTOT);
    if (nEnd <= nStart) return;

    int t = threadIdx.x, lane = t & 63, w = t >> 6;
    int wk = w & 3, wi = w >> 2;           // compute roles: 64k x 64i / wave
    int l15 = lane & 15, lhi = lane >> 4;
    int rg = w >> 1, qh = w & 1;           // staging roles: row-group, q-half

    unsigned EtB = (unsigned)(size_t)&Et[0][0];
    unsigned XtB = (unsigned)(size_t)&Xt[0][0];

    int q0 = qh * 2, q1 = q0 + 1;
    int d0 = ((lane & 3) + q0) & 3, d1 = ((lane & 3) + q1) & 3;
    int g0 = q0 * 16 + (lane >> 2), g1 = q1 * 16 + (lane >> 2);
    unsigned wb0 = (unsigned)((rg * 16 + (g0 >> 2)) * 128 + d0 * 32 + (g0 & 3) * 8);
    unsigned wb1 = (unsigned)((rg * 16 + (g1 >> 2)) * 128 + d1 * 32 + (g1 & 3) * 8);
    unsigned aB = EtB + (unsigned)(lhi * 4096 + wk * 512 + l15 * 8);
    unsigned bB = XtB + (unsigned)(lhi * 4096 + wi * 512 + l15 * 8);

    f32x4 vE0, vE1, vX0, vX1;
    f32x4 acc[4][4] = {};
    int nwin = (nEnd - nStart + 31) >> 5;

#define G1_LOAD(WIN)                                                        \
    {                                                                       \
        int nb_ = nStart + (WIN) * 32 + rg * 4;                             \
        int r0_ = nb_ + d0, r1_ = nb_ + d1;                                 \
        int a0_ = (r0_ < nEnd) ? r0_ : nStart;                              \
        int a1_ = (r1_ < nEnd) ? r1_ : nStart;                              \
        float m0_ = (r0_ < nEnd) ? 1.f : 0.f;                               \
        float m1_ = (r1_ < nEnd) ? 1.f : 0.f;                               \
        vE0 = *(const f32x4*)(E + (size_t)a0_ * 256 + g0 * 4) * m0_;        \
        vE1 = *(const f32x4*)(E + (size_t)a1_ * 256 + g1 * 4) * m1_;        \
        vX0 = *(const f32x4*)(X + (size_t)a0_ * 256 + g0 * 4) * m0_;        \
        vX1 = *(const f32x4*)(X + (size_t)a1_ * 256 + g1 * 4) * m1_;        \
    }

#define G1_WRITE(BUF)                                                       \
    {                                                                       \
        unsigned bo_ = (unsigned)(BUF) * 16384u;                            \
        *(u32x2*)((char*)Et + bo_ + wb0) =                                  \
            (u32x2){packbf2(vE0[0], vE0[1]), packbf2(vE0[2], vE0[3])};      \
        *(u32x2*)((char*)Et + bo_ + wb1) =                                  \
            (u32x2){packbf2(vE1[0], vE1[1]), packbf2(vE1[2], vE1[3])};      \
        *(u32x2*)((char*)Xt + bo_ + wb0) =                                  \
            (u32x2){packbf2(vX0[0], vX0[1]), packbf2(vX0[2], vX0[3])};      \
        *(u32x2*)((char*)Xt + bo_ + wb1) =                                  \
            (u32x2){packbf2(vX1[0], vX1[1]), packbf2(vX1[2], vX1[3])};      \
    }

#define G1_COMPUTE(BUF)                                                     \
    {                                                                       \
        unsigned bo_ = (unsigned)(BUF) * 16384u;                            \
        unsigned aB_ = aB + bo_, bB_ = bB + bo_;                            \
        s16x4 ta0[4], ta1[4], tb0[4], tb1[4];                               \
        _Pragma("unroll") for (int m = 0; m < 4; ++m) {                     \
            ta0[m] = trread(aB_ + m * 128);                                 \
            ta1[m] = trread2k(aB_ + m * 128);                               \
        }                                                                   \
        _Pragma("unroll") for (int c = 0; c < 4; ++c) {                     \
            tb0[c] = trread(bB_ + c * 128);                                 \
            tb1[c] = trread2k(bB_ + c * 128);                               \
        }                                                                   \
        LGKM0_FENCE();                                                      \
        s16x8 a[4], b[4];                                                   \
        _Pragma("unroll") for (int m = 0; m < 4; ++m) a[m] = cat44(ta0[m], ta1[m]); \
        _Pragma("unroll") for (int c = 0; c < 4; ++c) b[c] = cat44(tb0[c], tb1[c]); \
        _Pragma("unroll") for (int m = 0; m < 4; ++m)                       \
            _Pragma("unroll") for (int c = 0; c < 4; ++c)                   \
                acc[m][c] = __builtin_amdgcn_mfma_f32_16x16x32_bf16(        \
                    a[m], b[c], acc[m][c], 0, 0, 0);                        \
    }

    G1_LOAD(0);
    G1_WRITE(0);
    G1_LOAD(1);
    asm volatile("s_waitcnt lgkmcnt(0)" ::: "memory");
    __builtin_amdgcn_s_barrier();
    for (int win = 0; win < nwin; ++win) {
        int cur = win & 1;
        G1_COMPUTE(cur);
        if (win + 1 < nwin) G1_WRITE(cur ^ 1);
        if (win + 2 < nwin) G1_LOAD(win + 2);
        asm volatile("s_waitcnt lgkmcnt(0)" ::: "memory");
        __builtin_amdgcn_s_barrier();
    }
#undef G1_LOAD
#undef G1_WRITE
#undef G1_COMPUTE

    u16* dst = Pp + (size_t)chunk * 65536;
#pragma unroll
    for (int m = 0; m < 4; ++m) {
#pragma unroll
        for (int cf = 0; cf < 4; ++cf) {
            int ii = wi * 64 + cf * 16 + l15;
#pragma unroll
            for (int r = 0; r < 4; ++r) {
                int kk = wk * 64 + m * 16 + lhi * 4 + r;
                dst[kk * 256 + ii] = bfbits(acc[m][cf][r]);
            }
        }
    }
}

// ---------------- kernel 3a: partial reduce (16 groups x 16 chunks) ------
__global__ void k_reduceA(const u32* __restrict__ Pp32,
                          f32x2* __restrict__ Pf, int cpg) {
    int g = blockIdx.x >> 7;                 // group
    int idx = (blockIdx.x & 127) * 256 + threadIdx.x;   // 0..32767
    int c0 = g * cpg;
    float s0 = 0.f, s1 = 0.f;
    for (int c = c0; c < c0 + cpg; ++c) {
        u32 vv = Pp32[(size_t)c * 32768 + idx];
        s0 += bf2f((u16)(vv & 0xffff));
        s1 += bf2f((u16)(vv >> 16));
    }
    Pf[(size_t)g * 32768 + idx] = (f32x2){s0, s1};
}

// ---------------- kernel 3b: final reduce -> Pb (bf16) -------------------
__global__ void k_reduceB(const f32x2* __restrict__ Pf,
                          u32* __restrict__ Pb32, int G) {
    int idx = blockIdx.x * 256 + threadIdx.x;   // 0..32767
    float s0 = 0.f, s1 = 0.f;
    for (int g = 0; g < G; ++g) {
        f32x2 v = Pf[(size_t)g * 32768 + idx];
        s0 += v[0]; s1 += v[1];
    }
    Pb32[idx] = packbf2(s0, s1);
}

// ---------------- kernel 4: T[c] = P @ W_c^T (17 small GEMMs) ------------
__global__ __launch_bounds__(256, 4) void k_smallgemm(
    const u16* __restrict__ Pb, const float* __restrict__ c0,
    const float* __restrict__ cjr, const float* __restrict__ cji,
    float* __restrict__ T) {
    int c = blockIdx.x >> 3;
    int k0 = (blockIdx.x & 7) * 32;
    const float* W = (c == 0) ? c0 : (c <= 8 ? (cjr + (size_t)(c - 1) * 65536)
                                             : (cji + (size_t)(c - 9) * 65536));
    int t = threadIdx.x, lane = t & 63, wi = t >> 6;
    int l15 = lane & 15, lhi = lane >> 4;
    f32x4 acc[2][4] = {};
    for (int is = 0; is < 256; is += 32) {
        s16x8 a[2], b[4];
#pragma unroll
        for (int m = 0; m < 2; ++m)
            a[m] = *(const s16x8*)(Pb + (k0 + m * 16 + l15) * 256 + is + lhi * 8);
#pragma unroll
        for (int cf = 0; cf < 4; ++cf)
            b[cf] = cvt8(W + (size_t)(wi * 64 + cf * 16 + l15) * 256 + is + lhi * 8);
#pragma unroll
        for (int m = 0; m < 2; ++m)
#pragma unroll
            for (int cf = 0; cf < 4; ++cf)
                acc[m][cf] = __builtin_amdgcn_mfma_f32_16x16x32_bf16(
                    a[m], b[cf], acc[m][cf], 0, 0, 0);
    }
    float* dst = T + (size_t)c * 65536;
#pragma unroll
    for (int m = 0; m < 2; ++m) {
#pragma unroll
        for (int cf = 0; cf < 4; ++cf) {
            int oo = wi * 64 + cf * 16 + l15;
#pragma unroll
            for (int r = 0; r < 4; ++r) {
                int kk = k0 + m * 16 + lhi * 4 + r;
                dst[kk * 256 + oo] = acc[m][cf][r];
            }
        }
    }
}

// ---------------- kernel 5: combine T -> Qt bf16 (weights fused) ---------
__global__ void k_combine(const float* __restrict__ T, const float* __restrict__ ev,
                          const float* __restrict__ hp, const float* __restrict__ ap,
                          u16* __restrict__ Qt) {
    int t = threadIdx.x;
    int k = blockIdx.x * 4 + (t >> 6);
    int o4 = (t & 63) * 4;
    float h = hp[0], alpha = ap[0];
    float tt = h * (ev[k] - alpha);
    float inv = 1.0f / (tt * tt + 1.0f);
    float bre = (tt * tt - 1.0f) * inv;
    float bim = -2.0f * tt * inv;
    float cr = bre, ci = bim;
    f32x4 q = *(const f32x4*)(T + (size_t)k * 256 + o4);
#pragma unroll
    for (int j = 0; j < 8; ++j) {
        f32x4 tr = *(const f32x4*)(T + (size_t)(1 + j) * 65536 + k * 256 + o4);
        f32x4 ti = *(const f32x4*)(T + (size_t)(9 + j) * 65536 + k * 256 + o4);
        q += 2.0f * (cr * tr - ci * ti);
        float nr = cr * bre - ci * bim;
        float ni = cr * bim + ci * bre;
        cr = nr; ci = ni;
    }
#pragma unroll
    for (int e = 0; e < 4; ++e) Qt[(size_t)(o4 + e) * 256 + k] = bfbits(q[e]);
}

// ---------------- kernel 6: out = E @ Q ----------------------------------
// r8-proven (reg-staged depth-2 pipeline, XCD swizzle); ~26 us, near floor.
__global__ __launch_bounds__(512, 4) void k_gemm2(
    const float* __restrict__ E, const u16* __restrict__ Qt,
    float* __restrict__ out) {
    __shared__ alignas(16) u16 Ebuf[2][32 * 256];   // 2 x 16 KB

    int b0 = blockIdx.x;
    int b = (b0 & 7) * 64 + (b0 >> 3);   // bijective XCD swizzle (512 = 8*64)
    int og = b & 1;
    int slab = b >> 1;                   // 0..255
    int tile0 = slab * 12 + min(slab, 53);   // 3125 = 256*12 + 53
    int nt = (slab < 53) ? 13 : 12;

    int t = threadIdx.x, lane = t & 63, w = t >> 6;
    int l15 = lane & 15, lhi = lane >> 4;
    int wn = w & 1, wo = w >> 1;         // wo 0..3
    int obase = og * 128 + wo * 32;
    int nrow = wn * 16 + l15;

    s16x8 af[2][8];
#pragma unroll
    for (int m = 0; m < 2; ++m)
#pragma unroll
        for (int ks = 0; ks < 8; ++ks)
            af[m][ks] = *(const s16x8*)(Qt + (size_t)(obase + m * 16 + l15) * 256 +
                                        ks * 32 + lhi * 8);

    f32x4 rvA[4], rvB[4];

#define G2_LOADE(TI, RV)                                                    \
    {                                                                       \
        int nb0_ = (tile0 + (TI)) * 32 + w * 4;                             \
        _Pragma("unroll") for (int j = 0; j < 4; ++j)                       \
            RV[j] = *(const f32x4*)(E + (size_t)(nb0_ + j) * 256 + lane * 4); \
    }

#define G2_WRITEE(RV, BUF)                                                  \
    _Pragma("unroll") for (int j = 0; j < 4; ++j) {                         \
        int r_ = w * 4 + j;                                                 \
        *(u32x2*)((char*)Ebuf[BUF] + r_ * 512 +                             \
                  (((lane >> 1) ^ (r_ & 7)) * 16) + (lane & 1) * 8) =       \
            (u32x2){packbf2(RV[j][0], RV[j][1]), packbf2(RV[j][2], RV[j][3])}; \
    }

#define G2_TILE(I, BUF, WRV, LRV)                                           \
    {                                                                       \
        f32x4 acc[2] = {};                                                  \
        const char* Eb_ = (const char*)Ebuf[BUF];                           \
        _Pragma("unroll") for (int ks = 0; ks < 8; ++ks) {                  \
            s16x8 ef = *(const s16x8*)(Eb_ + nrow * 512 +                   \
                        (((ks * 4 + lhi) ^ (nrow & 7)) * 16));              \
            _Pragma("unroll") for (int m = 0; m < 2; ++m)                   \
                acc[m] = __builtin_amdgcn_mfma_f32_16x16x32_bf16(           \
                    af[m][ks], ef, acc[m], 0, 0, 0);                        \
        }                                                                   \
        int n_ = (tile0 + (I)) * 32 + wn * 16 + l15;                        \
        _Pragma("unroll") for (int m = 0; m < 2; ++m)                       \
            *(f32x4*)(out + (size_t)n_ * 256 + obase + m * 16 + lhi * 4) =  \
                acc[m];                                                     \
        if ((I) + 1 < nt) G2_WRITEE(WRV, (BUF) ^ 1);                        \
        if ((I) + 2 < nt) G2_LOADE((I) + 2, LRV);                           \
        asm volatile("s_waitcnt lgkmcnt(0)" ::: "memory");                  \
        __builtin_amdgcn_s_barrier();                                       \
    }

    G2_LOADE(0, rvA);
    G2_WRITEE(rvA, 0);                    // prologue vmcnt stall (once)
    G2_LOADE(1, rvB);
    asm volatile("s_waitcnt lgkmcnt(0)" ::: "memory");
    __builtin_amdgcn_s_barrier();

    for (int i = 0; i < nt; i += 2) {
        G2_TILE(i, 0, rvB, rvA);          // even tile: buf0; write rvB->buf1
        if (i + 1 < nt)
            G2_TILE(i + 1, 1, rvA, rvB);  // odd tile: buf1; write rvA->buf0
    }
#undef G2_LOADE
#undef G2_WRITEE
#undef G2_TILE
}

// ---------------- host ---------------------------------------------------
extern "C" void kernel_launch(void* const* d_in, const int* in_sizes, int n_in,
                              void* d_out, int out_size, void* d_ws, size_t ws_size,
                              hipStream_t stream) {
    const float* x   = (const float*)d_in[0];
    const float* ev  = (const float*)d_in[1];
    const float* E   = (const float*)d_in[2];
    const float* hp  = (const float*)d_in[3];
    const float* ap  = (const float*)d_in[4];
    const float* c0  = (const float*)d_in[5];
    const float* cjr = (const float*)d_in[6];
    const float* cji = (const float*)d_in[7];
    float* out = (float*)d_out;

    char* ws = (char*)d_ws;
    u16*   Pb = (u16*)(ws + 16384);               // 128 KB
    u16*   Qt = (u16*)(ws + 147456);              // 128 KB
    float* T  = (float*)(ws + 278528);            // 17*256 KB -> 4.73 MB

    // d_out scratch layout (102.4 MB total), consumed before gemm2
    // overwrites it (stream-ordered), all regions fully written every call:
    //   [0, 33.55 MB)       Pp: 256 chunks x 128 KB bf16 partials
    //   [33.55, 37.75 MB)   Pf: 16 groups x 32768 f32x2 partial sums
    u16* Pp = (u16*)d_out;
    f32x2* Pf = (f32x2*)((char*)d_out + 33554432);
    const int chunks = 256;
    const int NB = 391;                           // 256*391 = 100096 >= NTOT
    const int G = 16, CPG = 16;                   // 16*16 = 256 exact

    k_gemm1<<<chunks, 1024, 0, stream>>>(E, x, Pp, NB);
    k_reduceA<<<G * 128, 256, 0, stream>>>((const u32*)Pp, Pf, CPG);
    k_reduceB<<<128, 256, 0, stream>>>(Pf, (u32*)Pb, G);
    k_smallgemm<<<17 * 8, 256, 0, stream>>>(Pb, c0, cjr, cji, T);
    k_combine<<<64, 256, 0, stream>>>(T, ev, hp, ap, Qt);
    k_gemm2<<<512, 512, 0, stream>>>(E, Qt, out);
}